// Round 13
// baseline (411.255 us; speedup 1.0000x reference)
//
#include <hip/hip_runtime.h>

// ---------- constants ----------
#define Bsz   8192
#define Tlen  20
#define OUT_VAL_OFF  57344      // 8192*7 (floats)
#define OUT_MEM_OFF  65536      // +8192  (floats)

// ws layout (bytes)
#define WS_GI     0            // float[100*384]  gi_table[v][g]
#define WS_D1     153600       // float[8*2*2*64] conv1 lookup (bank-rotated)
#define WS_WT     161792       // float[256*512]  [k][u] actor_w1|critic_w1
#define WS_WHF    686080       // float[128*384]  WhhT[k][g] (fp32, legacy)
#define WS_LWT    882688       // float[256*512]  [k][g] k<128: wih, else whh
#define WS_LB     1406976      // float[512]  (bih+bhh)
#define WS_C2W    1409024      // float[16384]  c2wT[(i*4+p)*64+o]
#define WS_C2B    1474560      // float[64]
#define WS_C3W    1474816      // float[32768]  c3wT[kk*128+o]
#define WS_C3B    1605888      // float[128]
#define WS_C1B    1606400      // float[64]
#define WS_BH     1606656      // float[384]  gru_bhh
#define WS_B1     1608192      // float[512]
#define WS_W2     1610240      // float[8*256]
#define WS_B2     1618432      // float[8]
#define WS_FLAG   1618464      // int
#define WS_WHB    1618496      // ushort[384*128] bf16 whh[g][k] (MFMA b-frags)

#define GBLK   512
#define GROWS  16
#define PREP_TASKS 453768

// MFMA fragment types
using frag16 = __attribute__((ext_vector_type(8))) short;   // 8 bf16 (4 VGPRs)
using fragf4 = __attribute__((ext_vector_type(4))) float;   // 4 fp32

// ---------- helpers ----------
__device__ __forceinline__ float bf2f(unsigned short u){
    union { unsigned int i; float f; } v; v.i = ((unsigned int)u) << 16; return v.f;
}
__device__ __forceinline__ unsigned short f2bf(float f){
    union { float f; unsigned int i; } v; v.f = f;
    unsigned int x = v.i;
    return (unsigned short)((x + 0x7fffu + ((x >> 16) & 1u)) >> 16);
}
__device__ __forceinline__ float sigm(float x){ return 1.0f / (1.0f + __expf(-x)); }
__device__ __forceinline__ float tanh_f(float x){ return 1.0f - 2.0f / (__expf(2.0f * x) + 1.0f); }

template<bool BF>
__device__ __forceinline__ float G(const void* p, int i){
    if (BF) return bf2f(((const unsigned short*)p)[i]);
    else    return ((const float*)p)[i];
}

// ======================================================================
// dtype sniff (verified across r1-12)
// ======================================================================
__global__ __launch_bounds__(256) void sniff_kernel(
    const unsigned short* __restrict__ we, int* __restrict__ flag)
{
    __shared__ int cnt;
    if (threadIdx.x == 0) cnt = 0;
    __syncthreads();
    int c = 0;
    for (int i = threadIdx.x; i < 2048; i += 256) {
        int e = (we[i] >> 7) & 0xFF;
        if (e >= 96 && e <= 160) c++;
    }
    atomicAdd(&cnt, c);
    __syncthreads();
    if (threadIdx.x == 0) *flag = (cnt >= 1792) ? 1 : 0;
}

// ======================================================================
// prep: canonicalize + fused/transposed tables. 453768 tasks.
// D1 now stored bank-rotated: D1[tkk*64 + ((o + tkk) & 63)].
// ======================================================================
template<bool BF>
__global__ __launch_bounds__(256) void prep_kernel(
    const int* __restrict__ flag,
    const void* word_emb, const void* gru_wih, const void* gru_bih,
    const void* col_emb, const void* obj_emb, const void* st_emb,
    const void* conv1_w, const void* conv1_b,
    const void* conv2_w, const void* conv2_b,
    const void* conv3_w, const void* conv3_b,
    const void* lstm_wih, const void* lstm_whh,
    const void* lstm_bih, const void* lstm_bhh,
    const void* actor_w1, const void* actor_b1,
    const void* actor_w2, const void* actor_b2,
    const void* critic_w1, const void* critic_b1,
    const void* critic_w2, const void* critic_b2,
    const void* gru_whh, const void* gru_bhh,
    float* __restrict__ ws0)
{
    if ((*flag != 0) != BF) return;
    int task = blockIdx.x * 256 + threadIdx.x;
    if (task >= PREP_TASKS) return;
    char* wsb = (char*)ws0;
    if (task < 38400) {
        int v = task / 384, g = task - v * 384;
        float acc = G<BF>(gru_bih, g);
        #pragma unroll
        for (int d = 0; d < 32; d++)
            acc += G<BF>(word_emb, v * 32 + d) * G<BF>(gru_wih, g * 32 + d);
        ((float*)(wsb + WS_GI))[task] = acc;
    } else if (task < 40448) {
        int i2 = task - 38400;
        int o = i2 & 63; int tkk = i2 >> 6;
        int kx = tkk & 1, ky = (tkk >> 1) & 1, t = tkk >> 2;
        int c = t & 1, ob = (t >> 1) & 1, s = (t >> 2) & 1;
        float acc = 0.f;
        #pragma unroll
        for (int i = 0; i < 48; i++) {
            float e;
            if (i < 16)      e = G<BF>(col_emb, c * 16 + i);
            else if (i < 32) e = G<BF>(obj_emb, ob * 16 + (i - 16));
            else             e = G<BF>(st_emb, s * 16 + (i - 32));
            acc += e * G<BF>(conv1_w, ((o * 48 + i) * 2 + ky) * 2 + kx);
        }
        ((float*)(wsb + WS_D1))[tkk * 64 + ((o + tkk) & 63)] = acc;  // rotated
    } else if (task < 171520) {
        int i3 = task - 40448;                 // WT[k][u]
        int k = i3 >> 9, u = i3 & 511;
        ((float*)(wsb + WS_WT))[i3] = (u < 256) ? G<BF>(actor_w1, u * 256 + k)
                                                : G<BF>(critic_w1, (u - 256) * 256 + k);
    } else if (task < 220672) {
        int i4 = task - 171520;                // WhhTf[k][g] (legacy fp32)
        int k = i4 / 384, g = i4 - k * 384;
        ((float*)(wsb + WS_WHF))[i4] = G<BF>(gru_whh, g * 128 + k);
    } else if (task < 351744) {
        int i = task - 220672;                 // LWT[k*512+g]
        int k = i >> 9, g = i & 511;
        ((float*)(wsb + WS_LWT))[i] = (k < 128) ? G<BF>(lstm_wih, g * 128 + k)
                                                : G<BF>(lstm_whh, g * 128 + (k - 128));
    } else if (task < 352256) {
        int i = task - 351744;
        ((float*)(wsb + WS_LB))[i] = G<BF>(lstm_bih, i) + G<BF>(lstm_bhh, i);
    } else if (task < 368640) {
        int i = task - 352256;                 // c2wT[(ii*4+pp)*64+o]
        int o = i & 63, pp = (i >> 6) & 3, ii = i >> 8;
        ((float*)(wsb + WS_C2W))[i] = G<BF>(conv2_w, o * 256 + ii * 4 + pp);
    } else if (task < 368704) {
        int i = task - 368640;
        ((float*)(wsb + WS_C2B))[i] = G<BF>(conv2_b, i);
    } else if (task < 401472) {
        int i = task - 368704;                 // c3wT[kk*128+o]
        int o = i & 127, kk = i >> 7;
        ((float*)(wsb + WS_C3W))[i] = G<BF>(conv3_w, o * 256 + kk);
    } else if (task < 401600) {
        int i = task - 401472;
        ((float*)(wsb + WS_C3B))[i] = G<BF>(conv3_b, i);
    } else if (task < 401664) {
        int i = task - 401600;
        ((float*)(wsb + WS_C1B))[i] = G<BF>(conv1_b, i);
    } else if (task < 402048) {
        int i = task - 401664;
        ((float*)(wsb + WS_BH))[i] = G<BF>(gru_bhh, i);
    } else if (task < 402560) {
        int i = task - 402048;
        ((float*)(wsb + WS_B1))[i] = (i < 256) ? G<BF>(actor_b1, i) : G<BF>(critic_b1, i - 256);
    } else if (task < 404608) {
        int i = task - 402560;
        int u = i >> 8, k = i & 255;
        ((float*)(wsb + WS_W2))[i] = (u < 7) ? G<BF>(actor_w2, u * 256 + k) : G<BF>(critic_w2, k);
    } else if (task < 404616) {
        int i = task - 404608;
        ((float*)(wsb + WS_B2))[i] = (i < 7) ? G<BF>(actor_b2, i) : G<BF>(critic_b2, 0);
    } else {
        int i = task - 404616;                 // WHB2: bf16 whh[g][k], row-major
        ((unsigned short*)(wsb + WS_WHB))[i] = f2bf(G<BF>(gru_whh, i));
    }
}

// ======================================================================
// conv+LSTM v2: 8 samples/block; LDS 39.6 KB -> 4 blocks/CU (was 48.6->3).
// Conflict fixes: sp2 [k][9]+writer-key swizzle (was 64-way), sxa [s][264]
// (conv3 writes consecutive, LSTM reads broadcast), D1 bank-rotated.
// sxa aliases sD1 (dead after conv1); h-load moved to conv2 phase.
// All fp32 — bit-identical math to r12.
// ======================================================================
template<bool BF>
__global__ __launch_bounds__(256) void conv_lstm_kernel(
    const int* __restrict__ flag,
    const int* __restrict__ image, const void* memory,
    const float* __restrict__ ws0,
    float* __restrict__ mem_out)
{
    if ((*flag != 0) != BF) return;
    const char* wsb = (const char*)ws0;
    const float* D1g  = (const float*)(wsb + WS_D1);
    const float* c1bF = (const float*)(wsb + WS_C1B);
    const float* c2wT = (const float*)(wsb + WS_C2W);
    const float* c2bF = (const float*)(wsb + WS_C2B);
    const float* c3wT = (const float*)(wsb + WS_C3W);
    const float* c3bF = (const float*)(wsb + WS_C3B);
    const float* lwt  = (const float*)(wsb + WS_LWT);
    const float* lbF  = (const float*)(wsb + WS_LB);

    __shared__ __align__(16) char smem[40584];
    float* sp1 = (float*)smem;                   // [op 576][s 8]     18432 B
    float* sp2 = (float*)(smem + 18432);         // [k 256][9] swz     9216 B
    float* sD1 = (float*)(smem + 27648);         // conv1 phase        8192 B
    float* sxa = (float*)(smem + 27648);         // [s 8][264] x|h     8448 B (alias)
    float* sc  = (float*)(smem + 36096);         // [s 8][128] c       4096 B
    unsigned char* stt = (unsigned char*)(smem + 40192);  // 392 B

    int tid = threadIdx.x;
    int b0 = blockIdx.x * 8;

    for (int i = tid; i < 2048; i += 256) sD1[i] = D1g[i];
    for (int i = tid; i < 392; i += 256) {
        int s = i / 49, p = i - s * 49;
        int base = ((b0 + s) * 49 + p) * 3;
        stt[i] = (unsigned char)(image[base + 1] | (image[base] << 1) | (image[base + 2] << 2));
    }
    for (int i = tid; i < 1024; i += 256) {      // c part -> sc[s][k]
        int s = i >> 7, k = i & 127;
        sc[s * 128 + k] = G<BF>(memory, (b0 + s) * 256 + 128 + k);
    }
    __syncthreads();

    // conv1 (rotated-D1 lookup) + relu + pool -> sp1[op][s]
    for (int task = tid; task < 4608; task += 256) {
        int s = task & 7;
        int op = task >> 3;
        int o = op / 9, p = op - o * 9;
        int py = p / 3, px = p - py * 3;
        float bo = c1bF[o];
        float mx = 0.f;
        #pragma unroll
        for (int dy = 0; dy < 2; dy++)
        #pragma unroll
        for (int dx = 0; dx < 2; dx++) {
            int y = 2 * py + dy, x = 2 * px + dx;
            float sum = bo;
            #pragma unroll
            for (int ky = 0; ky < 2; ky++)
            #pragma unroll
            for (int kx = 0; kx < 2; kx++) {
                int t = stt[s * 49 + (y + ky) * 7 + (x + kx)];
                int tkk = t * 4 + ky * 2 + kx;
                sum += sD1[tkk * 64 + ((o + tkk) & 63)];
            }
            mx = fmaxf(mx, sum);
        }
        sp1[op * 8 + s] = mx;
    }
    __syncthreads();   // sD1 dead from here

    // conv2 + relu -> sp2 [row=ot*4+p][col swz by ot>>3]; also h -> sxa
    {
        int ot = tid & 63, st4 = tid >> 6;
        int s0 = st4 * 2;
        float b = c2bF[ot];
        float acc[4][2];
        #pragma unroll
        for (int p = 0; p < 4; p++) { acc[p][0] = b; acc[p][1] = b; }
        for (int i = 0; i < 64; i++) {
            float w0 = c2wT[(i * 4 + 0) * 64 + ot];
            float w1 = c2wT[(i * 4 + 1) * 64 + ot];
            float w2 = c2wT[(i * 4 + 2) * 64 + ot];
            float w3 = c2wT[(i * 4 + 3) * 64 + ot];
            #pragma unroll
            for (int ss = 0; ss < 2; ss++) {
                const float* vr = sp1 + i * 72 + s0 + ss;
                float v0 = vr[0],  v1 = vr[8],  v2 = vr[16];
                float v3 = vr[24], v4 = vr[32], v5 = vr[40];
                float v6 = vr[48], v7 = vr[56], v8 = vr[64];
                acc[0][ss] += w0 * v0 + w1 * v1 + w2 * v3 + w3 * v4;
                acc[1][ss] += w0 * v1 + w1 * v2 + w2 * v4 + w3 * v5;
                acc[2][ss] += w0 * v3 + w1 * v4 + w2 * v6 + w3 * v7;
                acc[3][ss] += w0 * v4 + w1 * v5 + w2 * v7 + w3 * v8;
            }
        }
        int key = ot >> 3;
        #pragma unroll
        for (int p = 0; p < 4; p++)
            #pragma unroll
            for (int ss = 0; ss < 2; ss++)
                sp2[(ot * 4 + p) * 9 + ((s0 + ss + key) & 7)] = fmaxf(acc[p][ss], 0.f);
    }
    for (int i = tid; i < 1024; i += 256) {      // h part -> sxa[s][128+k]
        int s = i >> 7, k = i & 127;
        sxa[s * 264 + 128 + k] = G<BF>(memory, (b0 + s) * 256 + k);
    }
    __syncthreads();

    // conv3 + relu -> sxa[s][ot]  (writes consecutive in ot: conflict-free)
    {
        int ot = tid & 127, st2 = tid >> 7;
        int s0 = st2 * 4;
        float b = c3bF[ot];
        float acc[4] = { b, b, b, b };
        for (int kk = 0; kk < 256; kk++) {
            float w = c3wT[kk * 128 + ot];
            const float* ar = sp2 + kk * 9;
            int sw = (kk >> 5) & 7;              // writer key: (kk>>2)>>3
            acc[0] = fmaf(w, ar[(s0 + 0 + sw) & 7], acc[0]);
            acc[1] = fmaf(w, ar[(s0 + 1 + sw) & 7], acc[1]);
            acc[2] = fmaf(w, ar[(s0 + 2 + sw) & 7], acc[2]);
            acc[3] = fmaf(w, ar[(s0 + 3 + sw) & 7], acc[3]);
        }
        #pragma unroll
        for (int ss = 0; ss < 4; ss++)
            sxa[(s0 + ss) * 264 + ot] = fmaxf(acc[ss], 0.f);
    }
    __syncthreads();

    // LSTM: reads sxa[r][k] broadcast; lwt fp32 k-major coalesced
    {
        int jt = tid & 31, r = tid >> 5;
        int j0 = jt * 4;
        float acc[4][4];
        #pragma unroll
        for (int q = 0; q < 4; q++)
            #pragma unroll
            for (int jj = 0; jj < 4; jj++)
                acc[q][jj] = lbF[q * 128 + j0 + jj];
        for (int k = 0; k < 256; k++) {
            float a = sxa[r * 264 + k];
            float4 wI = *(const float4*)(lwt + k * 512 + j0);
            float4 wF = *(const float4*)(lwt + k * 512 + 128 + j0);
            float4 wG = *(const float4*)(lwt + k * 512 + 256 + j0);
            float4 wO = *(const float4*)(lwt + k * 512 + 384 + j0);
            acc[0][0] = fmaf(wI.x, a, acc[0][0]); acc[0][1] = fmaf(wI.y, a, acc[0][1]);
            acc[0][2] = fmaf(wI.z, a, acc[0][2]); acc[0][3] = fmaf(wI.w, a, acc[0][3]);
            acc[1][0] = fmaf(wF.x, a, acc[1][0]); acc[1][1] = fmaf(wF.y, a, acc[1][1]);
            acc[1][2] = fmaf(wF.z, a, acc[1][2]); acc[1][3] = fmaf(wF.w, a, acc[1][3]);
            acc[2][0] = fmaf(wG.x, a, acc[2][0]); acc[2][1] = fmaf(wG.y, a, acc[2][1]);
            acc[2][2] = fmaf(wG.z, a, acc[2][2]); acc[2][3] = fmaf(wG.w, a, acc[2][3]);
            acc[3][0] = fmaf(wO.x, a, acc[3][0]); acc[3][1] = fmaf(wO.y, a, acc[3][1]);
            acc[3][2] = fmaf(wO.z, a, acc[3][2]); acc[3][3] = fmaf(wO.w, a, acc[3][3]);
        }
        #pragma unroll
        for (int jj = 0; jj < 4; jj++) {
            float ig = sigm(acc[0][jj]);
            float fg = sigm(acc[1][jj]);
            float gv = tanh_f(acc[2][jj]);
            float og = sigm(acc[3][jj]);
            float cv = sc[r * 128 + j0 + jj];
            float cn = fg * cv + ig * gv;
            float hn = og * tanh_f(cn);
            mem_out[(b0 + r) * 256 + j0 + jj]       = hn;
            mem_out[(b0 + r) * 256 + 128 + j0 + jj] = cn;
        }
    }
}

// ======================================================================
// GRU scan + heads v6 (r12, verified): MFMA scan, register B-frags.
// ======================================================================
__global__ __launch_bounds__(512) void gru_head_kernel(
    const int* __restrict__ text, const float* __restrict__ ws0,
    const float* __restrict__ mem_out,
    float* __restrict__ out_lp, float* __restrict__ out_val)
{
    const char* wsb = (const char*)ws0;
    const unsigned short* whb2 = (const unsigned short*)(wsb + WS_WHB);
    const float* gi_table = (const float*)(wsb + WS_GI);
    const float* bhF      = (const float*)(wsb + WS_BH);
    const float* WTf      = (const float*)(wsb + WS_WT);
    const float* b1F      = (const float*)(wsb + WS_B1);
    const float* W2f      = (const float*)(wsb + WS_W2);
    const float* B2f      = (const float*)(wsb + WS_B2);

    __shared__ __align__(16) unsigned short sHt[16 * 136];  // h bf16, [r][k] stride 136
    __shared__ __align__(16) float sBuf[12288];             // scan: sGi; head: sHid|sH2|sHg
    __shared__ float sScore[128];
    __shared__ int   sTok[16];

    float* sGi  = sBuf;            // [r][g] 6144 floats
    float* sHid = sBuf;            // [512][16] swizzled (head)
    float* sH2  = sBuf + 8192;     // [128][16] lstm h (head)
    float* sHg  = sBuf + 10240;    // [128][16] gru h (head)

    int tid = threadIdx.x;
    int rbase = blockIdx.x * GROWS;
    int wave = tid >> 6, lane = tid & 63;
    int quad = lane >> 4, l16 = lane & 15;
    int j = wave * 16 + l16;
    int m0 = quad * 4;

    frag16 Bf[3][4];
    #pragma unroll
    for (int grp = 0; grp < 3; grp++)
        #pragma unroll
        for (int kc = 0; kc < 4; kc++)
            Bf[grp][kc] = *(const frag16*)(whb2 + (grp * 128 + j) * 128 + kc * 32 + quad * 8);

    float bhj[3] = { bhF[j], bhF[128 + j], bhF[256 + j] };
    float hprev[4] = { 0.f, 0.f, 0.f, 0.f };

    for (int i = tid; i < 16 * 136; i += 512) sHt[i] = 0;
    __syncthreads();

    for (int t = 0; t < Tlen; t++) {
        if (tid < 16) sTok[tid] = text[(rbase + tid) * Tlen + t];
        __syncthreads();   // B1: sTok ready; prev-t h writes visible

        for (int i = tid; i < 1536; i += 512) {
            int r = i / 96, off = (i - r * 96) * 4;
            *(float4*)(sGi + r * 384 + off) =
                *(const float4*)(gi_table + sTok[r] * 384 + off);
        }
        frag16 Af[4];
        #pragma unroll
        for (int kc = 0; kc < 4; kc++)
            Af[kc] = *(const frag16*)(sHt + l16 * 136 + kc * 32 + quad * 8);

        fragf4 accR = {0.f,0.f,0.f,0.f}, accZ = {0.f,0.f,0.f,0.f}, accN = {0.f,0.f,0.f,0.f};
        #pragma unroll
        for (int kc = 0; kc < 4; kc++) {
            accR = __builtin_amdgcn_mfma_f32_16x16x32_bf16(Af[kc], Bf[0][kc], accR, 0, 0, 0);
            accZ = __builtin_amdgcn_mfma_f32_16x16x32_bf16(Af[kc], Bf[1][kc], accZ, 0, 0, 0);
            accN = __builtin_amdgcn_mfma_f32_16x16x32_bf16(Af[kc], Bf[2][kc], accN, 0, 0, 0);
        }
        __syncthreads();   // B2: sGi staged; all A-frag reads done

        #pragma unroll
        for (int reg = 0; reg < 4; reg++) {
            int m = m0 + reg;
            float gr = sGi[m * 384 + j];
            float gz = sGi[m * 384 + 128 + j];
            float gn = sGi[m * 384 + 256 + j];
            float rg = sigm(gr + accR[reg] + bhj[0]);
            float zg = sigm(gz + accZ[reg] + bhj[1]);
            float ng = tanh_f(gn + rg * (accN[reg] + bhj[2]));
            float hn = (1.f - zg) * ng + zg * hprev[reg];
            unsigned short hb = f2bf(hn);
            hprev[reg] = bf2f(hb);
            sHt[m * 136 + j] = hb;
        }
    }
    __syncthreads();

    for (int i = tid; i < 2048; i += 512) {
        int k = i >> 4, r = i & 15;
        sH2[k * 16 + r] = mem_out[(rbase + r) * 256 + k];
    }
    for (int i = tid; i < 2048; i += 512) {
        int k = i >> 4, r = i & 15;
        sHg[k * 16 + r] = bf2f(sHt[r * 136 + k]);
    }
    __syncthreads();

    {
        int ut = tid & 255, rg = tid >> 8;
        int u0 = ut * 2, rr0 = rg * 8;
        float acc[2][8] = {};
        for (int k = 0; k < 256; k++) {
            float2 w = *(const float2*)(WTf + k * 512 + u0);
            const float* ap = (k < 128) ? (sH2 + k * 16 + rr0)
                                        : (sHg + (k - 128) * 16 + rr0);
            float4 a0 = *(const float4*)(ap);
            float4 a1 = *(const float4*)(ap + 4);
            float av[8] = { a0.x, a0.y, a0.z, a0.w, a1.x, a1.y, a1.z, a1.w };
            #pragma unroll
            for (int rr = 0; rr < 8; rr++) {
                acc[0][rr] = fmaf(w.x, av[rr], acc[0][rr]);
                acc[1][rr] = fmaf(w.y, av[rr], acc[1][rr]);
            }
        }
        #pragma unroll
        for (int uu = 0; uu < 2; uu++) {
            int u = u0 + uu;
            float b = b1F[u];
            #pragma unroll
            for (int rr = 0; rr < 8; rr++) {
                int r = rr0 + rr;
                sHid[u * 16 + ((r + (u >> 1)) & 15)] = tanh_f(acc[uu][rr] + b);
            }
        }
    }
    __syncthreads();

    {
        int r = tid >> 3, i = tid & 7;
        float acc2 = 0.f;
        if (tid < 128) {
            acc2 = B2f[i];
            const float* wrp = W2f + i * 256;
            int ubase = (i < 7) ? 0 : 256;
            for (int k = 0; k < 256; k++) {
                int u = ubase + k;
                acc2 += wrp[k] * sHid[u * 16 + ((r + (u >> 1)) & 15)];
            }
            sScore[tid] = acc2;
        }
        __syncthreads();
        if (tid < 128) {
            const float* sr = sScore + r * 8;
            float m = sr[0];
            #pragma unroll
            for (int a = 1; a < 7; a++) m = fmaxf(m, sr[a]);
            float se = 0.f;
            #pragma unroll
            for (int a = 0; a < 7; a++) se += __expf(sr[a] - m);
            float lse = m + __logf(se);
            if (i < 7) out_lp[(rbase + r) * 7 + i] = acc2 - lse;
            else       out_val[rbase + r] = acc2;
        }
    }
}

// ======================================================================
extern "C" void kernel_launch(void* const* d_in, const int* in_sizes, int n_in,
                              void* d_out, int out_size, void* d_ws, size_t ws_size,
                              hipStream_t stream) {
    const int*  image  = (const int*)d_in[0];
    const void* memory = d_in[1];
    const int*  text   = (const int*)d_in[2];

    char* wsb = (char*)d_ws;
    float* ws0  = (float*)wsb;
    int*   flag = (int*)(wsb + WS_FLAG);

    float* out = (float*)d_out;
    float* out_lp  = out;
    float* out_val = out + OUT_VAL_OFF;
    float* mem_out = out + OUT_MEM_OFF;

    sniff_kernel<<<1, 256, 0, stream>>>((const unsigned short*)d_in[16], flag);

    const int PREP_GRID = (PREP_TASKS + 255) / 256;
    prep_kernel<true><<<PREP_GRID, 256, 0, stream>>>(flag,
        d_in[16], d_in[17], d_in[19], d_in[4], d_in[3], d_in[5],
        d_in[6], d_in[7], d_in[8], d_in[9], d_in[10], d_in[11],
        d_in[12], d_in[13], d_in[14], d_in[15],
        d_in[21], d_in[22], d_in[23], d_in[24],
        d_in[25], d_in[26], d_in[27], d_in[28],
        d_in[18], d_in[20], ws0);
    prep_kernel<false><<<PREP_GRID, 256, 0, stream>>>(flag,
        d_in[16], d_in[17], d_in[19], d_in[4], d_in[3], d_in[5],
        d_in[6], d_in[7], d_in[8], d_in[9], d_in[10], d_in[11],
        d_in[12], d_in[13], d_in[14], d_in[15],
        d_in[21], d_in[22], d_in[23], d_in[24],
        d_in[25], d_in[26], d_in[27], d_in[28],
        d_in[18], d_in[20], ws0);

    conv_lstm_kernel<true><<<Bsz / 8, 256, 0, stream>>>(flag, image, memory, ws0, mem_out);
    conv_lstm_kernel<false><<<Bsz / 8, 256, 0, stream>>>(flag, image, memory, ws0, mem_out);

    gru_head_kernel<<<GBLK, 512, 0, stream>>>(text, ws0, mem_out, out_lp, out_val);
}

// Round 14
// 305.255 us; speedup vs baseline: 1.3472x; 1.3472x over previous
//
#include <hip/hip_runtime.h>

// ---------- constants ----------
#define Bsz   8192
#define Tlen  20
#define OUT_VAL_OFF  57344      // 8192*7 (floats)
#define OUT_MEM_OFF  65536      // +8192  (floats)

// ws layout (bytes)
#define WS_GI     0            // float[100*384]  gi_table[v][g]
#define WS_D1     153600       // float[8*2*2*64] conv1 lookup (bank-rotated)
#define WS_WT     161792       // float[256*512]  [k][u] actor_w1|critic_w1
#define WS_WHF    686080       // float[128*384]  (legacy, unused)
#define WS_LWT    882688       // float[256*512]  (legacy, unused)
#define WS_LB     1406976      // float[512]  (bih+bhh)
#define WS_C2W    1409024      // float[16384]  c2wT[(i*4+p)*64+o]
#define WS_C2B    1474560      // float[64]
#define WS_C3W    1474816      // float[32768]  c3wT[kk*128+o]
#define WS_C3B    1605888      // float[128]
#define WS_C1B    1606400      // float[64]
#define WS_BH     1606656      // float[384]  gru_bhh
#define WS_B1     1608192      // float[512]
#define WS_W2     1610240      // float[8*256]
#define WS_B2     1618432      // float[8]
#define WS_FLAG   1618464      // int
#define WS_WHB    1618496      // ushort[384*128] bf16 whh[g][k] (GRU MFMA B)
#define WS_LWTB   1716800      // ushort[512*256] bf16 lstm [g][k] k<128 wih else whh

#define GBLK   512
#define GROWS  16
#define PREP_TASKS 584840

// MFMA fragment types
using frag16 = __attribute__((ext_vector_type(8))) short;   // 8 bf16 (4 VGPRs)
using fragf4 = __attribute__((ext_vector_type(4))) float;   // 4 fp32

// ---------- helpers ----------
__device__ __forceinline__ float bf2f(unsigned short u){
    union { unsigned int i; float f; } v; v.i = ((unsigned int)u) << 16; return v.f;
}
__device__ __forceinline__ unsigned short f2bf(float f){
    union { float f; unsigned int i; } v; v.f = f;
    unsigned int x = v.i;
    return (unsigned short)((x + 0x7fffu + ((x >> 16) & 1u)) >> 16);
}
__device__ __forceinline__ float sigm(float x){ return 1.0f / (1.0f + __expf(-x)); }
__device__ __forceinline__ float tanh_f(float x){ return 1.0f - 2.0f / (__expf(2.0f * x) + 1.0f); }

template<bool BF>
__device__ __forceinline__ float G(const void* p, int i){
    if (BF) return bf2f(((const unsigned short*)p)[i]);
    else    return ((const float*)p)[i];
}

// ======================================================================
// dtype sniff (verified across r1-13)
// ======================================================================
__global__ __launch_bounds__(256) void sniff_kernel(
    const unsigned short* __restrict__ we, int* __restrict__ flag)
{
    __shared__ int cnt;
    if (threadIdx.x == 0) cnt = 0;
    __syncthreads();
    int c = 0;
    for (int i = threadIdx.x; i < 2048; i += 256) {
        int e = (we[i] >> 7) & 0xFF;
        if (e >= 96 && e <= 160) c++;
    }
    atomicAdd(&cnt, c);
    __syncthreads();
    if (threadIdx.x == 0) *flag = (cnt >= 1792) ? 1 : 0;
}

// ======================================================================
// prep: canonicalize + fused/transposed tables. 584840 tasks.
// ======================================================================
template<bool BF>
__global__ __launch_bounds__(256) void prep_kernel(
    const int* __restrict__ flag,
    const void* word_emb, const void* gru_wih, const void* gru_bih,
    const void* col_emb, const void* obj_emb, const void* st_emb,
    const void* conv1_w, const void* conv1_b,
    const void* conv2_w, const void* conv2_b,
    const void* conv3_w, const void* conv3_b,
    const void* lstm_wih, const void* lstm_whh,
    const void* lstm_bih, const void* lstm_bhh,
    const void* actor_w1, const void* actor_b1,
    const void* actor_w2, const void* actor_b2,
    const void* critic_w1, const void* critic_b1,
    const void* critic_w2, const void* critic_b2,
    const void* gru_whh, const void* gru_bhh,
    float* __restrict__ ws0)
{
    if ((*flag != 0) != BF) return;
    int task = blockIdx.x * 256 + threadIdx.x;
    if (task >= PREP_TASKS) return;
    char* wsb = (char*)ws0;
    if (task < 38400) {
        int v = task / 384, g = task - v * 384;
        float acc = G<BF>(gru_bih, g);
        #pragma unroll
        for (int d = 0; d < 32; d++)
            acc += G<BF>(word_emb, v * 32 + d) * G<BF>(gru_wih, g * 32 + d);
        ((float*)(wsb + WS_GI))[task] = acc;
    } else if (task < 40448) {
        int i2 = task - 38400;
        int o = i2 & 63; int tkk = i2 >> 6;
        int kx = tkk & 1, ky = (tkk >> 1) & 1, t = tkk >> 2;
        int c = t & 1, ob = (t >> 1) & 1, s = (t >> 2) & 1;
        float acc = 0.f;
        #pragma unroll
        for (int i = 0; i < 48; i++) {
            float e;
            if (i < 16)      e = G<BF>(col_emb, c * 16 + i);
            else if (i < 32) e = G<BF>(obj_emb, ob * 16 + (i - 16));
            else             e = G<BF>(st_emb, s * 16 + (i - 32));
            acc += e * G<BF>(conv1_w, ((o * 48 + i) * 2 + ky) * 2 + kx);
        }
        ((float*)(wsb + WS_D1))[tkk * 64 + ((o + tkk) & 63)] = acc;  // rotated
    } else if (task < 171520) {
        int i3 = task - 40448;                 // WT[k][u]
        int k = i3 >> 9, u = i3 & 511;
        ((float*)(wsb + WS_WT))[i3] = (u < 256) ? G<BF>(actor_w1, u * 256 + k)
                                                : G<BF>(critic_w1, (u - 256) * 256 + k);
    } else if (task < 220672) {
        int i4 = task - 171520;                // legacy WhhTf (unused)
        int k = i4 / 384, g = i4 - k * 384;
        ((float*)(wsb + WS_WHF))[i4] = G<BF>(gru_whh, g * 128 + k);
    } else if (task < 351744) {
        int i = task - 220672;                 // legacy LWT fp32 (unused)
        int k = i >> 9, g = i & 511;
        ((float*)(wsb + WS_LWT))[i] = (k < 128) ? G<BF>(lstm_wih, g * 128 + k)
                                                : G<BF>(lstm_whh, g * 128 + (k - 128));
    } else if (task < 352256) {
        int i = task - 351744;
        ((float*)(wsb + WS_LB))[i] = G<BF>(lstm_bih, i) + G<BF>(lstm_bhh, i);
    } else if (task < 368640) {
        int i = task - 352256;                 // c2wT[(ii*4+pp)*64+o]
        int o = i & 63, pp = (i >> 6) & 3, ii = i >> 8;
        ((float*)(wsb + WS_C2W))[i] = G<BF>(conv2_w, o * 256 + ii * 4 + pp);
    } else if (task < 368704) {
        int i = task - 368640;
        ((float*)(wsb + WS_C2B))[i] = G<BF>(conv2_b, i);
    } else if (task < 401472) {
        int i = task - 368704;                 // c3wT[kk*128+o]
        int o = i & 127, kk = i >> 7;
        ((float*)(wsb + WS_C3W))[i] = G<BF>(conv3_w, o * 256 + kk);
    } else if (task < 401600) {
        int i = task - 401472;
        ((float*)(wsb + WS_C3B))[i] = G<BF>(conv3_b, i);
    } else if (task < 401664) {
        int i = task - 401600;
        ((float*)(wsb + WS_C1B))[i] = G<BF>(conv1_b, i);
    } else if (task < 402048) {
        int i = task - 401664;
        ((float*)(wsb + WS_BH))[i] = G<BF>(gru_bhh, i);
    } else if (task < 402560) {
        int i = task - 402048;
        ((float*)(wsb + WS_B1))[i] = (i < 256) ? G<BF>(actor_b1, i) : G<BF>(critic_b1, i - 256);
    } else if (task < 404608) {
        int i = task - 402560;
        int u = i >> 8, k = i & 255;
        ((float*)(wsb + WS_W2))[i] = (u < 7) ? G<BF>(actor_w2, u * 256 + k) : G<BF>(critic_w2, k);
    } else if (task < 404616) {
        int i = task - 404608;
        ((float*)(wsb + WS_B2))[i] = (i < 7) ? G<BF>(actor_b2, i) : G<BF>(critic_b2, 0);
    } else if (task < 453768) {
        int i = task - 404616;                 // WHB2: bf16 whh[g][k], row-major
        ((unsigned short*)(wsb + WS_WHB))[i] = f2bf(G<BF>(gru_whh, i));
    } else {
        int i = task - 453768;                 // LWTB: bf16 lstm [g][k]
        int g = i >> 8, k = i & 255;
        float v = (k < 128) ? G<BF>(lstm_wih, g * 128 + k)
                            : G<BF>(lstm_whh, g * 128 + (k - 128));
        ((unsigned short*)(wsb + WS_LWTB))[i] = f2bf(v);
    }
}

// ======================================================================
// conv kernel: conv1/2/3 only, 8 samples/block. x (fp32) written into
// mem_out's h-slot (gru_head reads it then overwrites with real h).
// LDS ~36 KB -> 4 blocks/CU. Dtype-free (tables only) -> single launch.
// ======================================================================
__global__ __launch_bounds__(256) void conv_kernel(
    const int* __restrict__ image,
    const float* __restrict__ ws0,
    float* __restrict__ mem_out)
{
    const char* wsb = (const char*)ws0;
    const float* D1g  = (const float*)(wsb + WS_D1);
    const float* c1bF = (const float*)(wsb + WS_C1B);
    const float* c2wT = (const float*)(wsb + WS_C2W);
    const float* c2bF = (const float*)(wsb + WS_C2B);
    const float* c3wT = (const float*)(wsb + WS_C3W);
    const float* c3bF = (const float*)(wsb + WS_C3B);

    __shared__ __align__(16) float sp1[576 * 8];     // 18432 B
    __shared__ __align__(16) float sp2[256 * 9];     //  9216 B (swizzled)
    __shared__ __align__(16) float sD1[2048];        //  8192 B
    __shared__ unsigned char stt[392];

    int tid = threadIdx.x;
    int b0 = blockIdx.x * 8;

    for (int i = tid; i < 2048; i += 256) sD1[i] = D1g[i];
    for (int i = tid; i < 392; i += 256) {
        int s = i / 49, p = i - s * 49;
        int base = ((b0 + s) * 49 + p) * 3;
        stt[i] = (unsigned char)(image[base + 1] | (image[base] << 1) | (image[base + 2] << 2));
    }
    __syncthreads();

    // conv1 (rotated-D1 lookup) + relu + pool -> sp1[op][s]
    for (int task = tid; task < 4608; task += 256) {
        int s = task & 7;
        int op = task >> 3;
        int o = op / 9, p = op - o * 9;
        int py = p / 3, px = p - py * 3;
        float bo = c1bF[o];
        float mx = 0.f;
        #pragma unroll
        for (int dy = 0; dy < 2; dy++)
        #pragma unroll
        for (int dx = 0; dx < 2; dx++) {
            int y = 2 * py + dy, x = 2 * px + dx;
            float sum = bo;
            #pragma unroll
            for (int ky = 0; ky < 2; ky++)
            #pragma unroll
            for (int kx = 0; kx < 2; kx++) {
                int t = stt[s * 49 + (y + ky) * 7 + (x + kx)];
                int tkk = t * 4 + ky * 2 + kx;
                sum += sD1[tkk * 64 + ((o + tkk) & 63)];
            }
            mx = fmaxf(mx, sum);
        }
        sp1[op * 8 + s] = mx;
    }
    __syncthreads();

    // conv2 + relu -> sp2 [row=ot*4+p][col swz by ot>>3]
    {
        int ot = tid & 63, st4 = tid >> 6;
        int s0 = st4 * 2;
        float b = c2bF[ot];
        float acc[4][2];
        #pragma unroll
        for (int p = 0; p < 4; p++) { acc[p][0] = b; acc[p][1] = b; }
        for (int i = 0; i < 64; i++) {
            float w0 = c2wT[(i * 4 + 0) * 64 + ot];
            float w1 = c2wT[(i * 4 + 1) * 64 + ot];
            float w2 = c2wT[(i * 4 + 2) * 64 + ot];
            float w3 = c2wT[(i * 4 + 3) * 64 + ot];
            #pragma unroll
            for (int ss = 0; ss < 2; ss++) {
                const float* vr = sp1 + i * 72 + s0 + ss;
                float v0 = vr[0],  v1 = vr[8],  v2 = vr[16];
                float v3 = vr[24], v4 = vr[32], v5 = vr[40];
                float v6 = vr[48], v7 = vr[56], v8 = vr[64];
                acc[0][ss] += w0 * v0 + w1 * v1 + w2 * v3 + w3 * v4;
                acc[1][ss] += w0 * v1 + w1 * v2 + w2 * v4 + w3 * v5;
                acc[2][ss] += w0 * v3 + w1 * v4 + w2 * v6 + w3 * v7;
                acc[3][ss] += w0 * v4 + w1 * v5 + w2 * v7 + w3 * v8;
            }
        }
        int key = ot >> 3;
        #pragma unroll
        for (int p = 0; p < 4; p++)
            #pragma unroll
            for (int ss = 0; ss < 2; ss++)
                sp2[(ot * 4 + p) * 9 + ((s0 + ss + key) & 7)] = fmaxf(acc[p][ss], 0.f);
    }
    __syncthreads();

    // conv3 + relu -> x straight to mem_out h-slot (fp32, coalesced in ot)
    {
        int ot = tid & 127, st2 = tid >> 7;
        int s0 = st2 * 4;
        float b = c3bF[ot];
        float acc[4] = { b, b, b, b };
        for (int kk = 0; kk < 256; kk++) {
            float w = c3wT[kk * 128 + ot];
            const float* ar = sp2 + kk * 9;
            int sw = (kk >> 5) & 7;
            acc[0] = fmaf(w, ar[(s0 + 0 + sw) & 7], acc[0]);
            acc[1] = fmaf(w, ar[(s0 + 1 + sw) & 7], acc[1]);
            acc[2] = fmaf(w, ar[(s0 + 2 + sw) & 7], acc[2]);
            acc[3] = fmaf(w, ar[(s0 + 3 + sw) & 7], acc[3]);
        }
        #pragma unroll
        for (int ss = 0; ss < 4; ss++)
            mem_out[(b0 + s0 + ss) * 256 + ot] = fmaxf(acc[ss], 0.f);
    }
}

// ======================================================================
// GRU scan + heads v7: + LSTM-MFMA pre-phase (M=16 samples, 8 waves,
// wave w owns lstm col j=16w+l16 for all 4 gates; B-frags streamed from
// LWTB). h lands directly in sH2 (head input) + mem_out. GRU scan and
// head phases unchanged from verified r12 (sH2 restrided to 20).
// ======================================================================
__global__ __launch_bounds__(512) void gru_head_kernel(
    const int* __restrict__ flag,
    const int* __restrict__ text, const void* memory,
    const float* __restrict__ ws0,
    float* __restrict__ mem_out,
    float* __restrict__ out_lp, float* __restrict__ out_val)
{
    const char* wsb = (const char*)ws0;
    const unsigned short* whb2 = (const unsigned short*)(wsb + WS_WHB);
    const unsigned short* lwtb = (const unsigned short*)(wsb + WS_LWTB);
    const float* gi_table = (const float*)(wsb + WS_GI);
    const float* bhF      = (const float*)(wsb + WS_BH);
    const float* WTf      = (const float*)(wsb + WS_WT);
    const float* b1F      = (const float*)(wsb + WS_B1);
    const float* W2f      = (const float*)(wsb + WS_W2);
    const float* B2f      = (const float*)(wsb + WS_B2);
    const float* lbF      = (const float*)(wsb + WS_LB);

    __shared__ __align__(16) unsigned short sHt[16 * 136];  // gru h bf16
    __shared__ __align__(16) float sBuf[12800];
    __shared__ float sScore[128];
    __shared__ int   sTok[16];

    unsigned short* sXA = (unsigned short*)sBuf;  // [16][264] lstm input (pre-phase)
    float* sGi  = sBuf;            // [r][g] 6144 floats (scan)
    float* sHid = sBuf;            // [512][16] swizzled (head)
    float* sH2  = sBuf + 8192;     // [128][20] lstm h (stride 20) -> 2560
    float* sHg  = sBuf + 10752;    // [128][16] gru h -> 2048 (total 12800)

    int tid = threadIdx.x;
    int rbase = blockIdx.x * GROWS;
    int wave = tid >> 6, lane = tid & 63;
    int quad = lane >> 4, l16 = lane & 15;
    int j = wave * 16 + l16;
    int m0 = quad * 4;
    const bool bfin = (*flag != 0);
    const unsigned short* mem16 = (const unsigned short*)memory;
    const float*          memf  = (const float*)memory;

    // ---- stage lstm input xa = [x | h] as bf16 ----
    for (int i = tid; i < 4096; i += 512) {
        int m = i >> 8, k = i & 255;
        float v;
        if (k < 128) v = mem_out[(rbase + m) * 256 + k];           // x from conv
        else v = bfin ? bf2f(mem16[(rbase + m) * 256 + (k - 128)])
                      : memf[(rbase + m) * 256 + (k - 128)];       // h
        sXA[m * 264 + k] = f2bf(v);
    }
    __syncthreads();

    // ---- LSTM MFMA: gates[16x512] = xa[16x256] @ lwtb^T ----
    {
        frag16 Ax[8];
        #pragma unroll
        for (int kc = 0; kc < 8; kc++)
            Ax[kc] = *(const frag16*)(sXA + l16 * 264 + kc * 32 + quad * 8);
        fragf4 aI = {0.f,0.f,0.f,0.f}, aF = {0.f,0.f,0.f,0.f};
        fragf4 aG = {0.f,0.f,0.f,0.f}, aO = {0.f,0.f,0.f,0.f};
        #pragma unroll
        for (int kc = 0; kc < 8; kc++) {
            int ko = kc * 32 + quad * 8;
            frag16 bI = *(const frag16*)(lwtb + (j)       * 256 + ko);
            frag16 bF = *(const frag16*)(lwtb + (128 + j) * 256 + ko);
            frag16 bG = *(const frag16*)(lwtb + (256 + j) * 256 + ko);
            frag16 bO = *(const frag16*)(lwtb + (384 + j) * 256 + ko);
            aI = __builtin_amdgcn_mfma_f32_16x16x32_bf16(Ax[kc], bI, aI, 0, 0, 0);
            aF = __builtin_amdgcn_mfma_f32_16x16x32_bf16(Ax[kc], bF, aF, 0, 0, 0);
            aG = __builtin_amdgcn_mfma_f32_16x16x32_bf16(Ax[kc], bG, aG, 0, 0, 0);
            aO = __builtin_amdgcn_mfma_f32_16x16x32_bf16(Ax[kc], bO, aO, 0, 0, 0);
        }
        float lbI = lbF[j], lbFg = lbF[128 + j], lbG = lbF[256 + j], lbO = lbF[384 + j];
        __syncthreads();   // sXA reads done (sH2 region untouched by staging)
        #pragma unroll
        for (int reg = 0; reg < 4; reg++) {
            int m = m0 + reg;
            float ig = sigm(aI[reg] + lbI);
            float fg = sigm(aF[reg] + lbFg);
            float gv = tanh_f(aG[reg] + lbG);
            float og = sigm(aO[reg] + lbO);
            float cv = bfin ? bf2f(mem16[(rbase + m) * 256 + 128 + j])
                            : memf[(rbase + m) * 256 + 128 + j];
            float cn = fg * cv + ig * gv;
            float hn = og * tanh_f(cn);
            mem_out[(rbase + m) * 256 + j]       = hn;
            mem_out[(rbase + m) * 256 + 128 + j] = cn;
            sH2[j * 20 + m] = hn;
        }
    }

    // ---- GRU: B-frags (loaded after LSTM regs retire) ----
    frag16 Bf[3][4];
    #pragma unroll
    for (int grp = 0; grp < 3; grp++)
        #pragma unroll
        for (int kc = 0; kc < 4; kc++)
            Bf[grp][kc] = *(const frag16*)(whb2 + (grp * 128 + j) * 128 + kc * 32 + quad * 8);

    float bhj[3] = { bhF[j], bhF[128 + j], bhF[256 + j] };
    float hprev[4] = { 0.f, 0.f, 0.f, 0.f };

    for (int i = tid; i < 16 * 136; i += 512) sHt[i] = 0;
    __syncthreads();

    for (int t = 0; t < Tlen; t++) {
        if (tid < 16) sTok[tid] = text[(rbase + tid) * Tlen + t];
        __syncthreads();   // B1: sTok ready; prev-t h writes visible

        for (int i = tid; i < 1536; i += 512) {
            int r = i / 96, off = (i - r * 96) * 4;
            *(float4*)(sGi + r * 384 + off) =
                *(const float4*)(gi_table + sTok[r] * 384 + off);
        }
        frag16 Af[4];
        #pragma unroll
        for (int kc = 0; kc < 4; kc++)
            Af[kc] = *(const frag16*)(sHt + l16 * 136 + kc * 32 + quad * 8);

        fragf4 accR = {0.f,0.f,0.f,0.f}, accZ = {0.f,0.f,0.f,0.f}, accN = {0.f,0.f,0.f,0.f};
        #pragma unroll
        for (int kc = 0; kc < 4; kc++) {
            accR = __builtin_amdgcn_mfma_f32_16x16x32_bf16(Af[kc], Bf[0][kc], accR, 0, 0, 0);
            accZ = __builtin_amdgcn_mfma_f32_16x16x32_bf16(Af[kc], Bf[1][kc], accZ, 0, 0, 0);
            accN = __builtin_amdgcn_mfma_f32_16x16x32_bf16(Af[kc], Bf[2][kc], accN, 0, 0, 0);
        }
        __syncthreads();   // B2: sGi staged; all A-frag reads done

        #pragma unroll
        for (int reg = 0; reg < 4; reg++) {
            int m = m0 + reg;
            float gr = sGi[m * 384 + j];
            float gz = sGi[m * 384 + 128 + j];
            float gn = sGi[m * 384 + 256 + j];
            float rg = sigm(gr + accR[reg] + bhj[0]);
            float zg = sigm(gz + accZ[reg] + bhj[1]);
            float ng = tanh_f(gn + rg * (accN[reg] + bhj[2]));
            float hn = (1.f - zg) * ng + zg * hprev[reg];
            unsigned short hb = f2bf(hn);
            hprev[reg] = bf2f(hb);
            sHt[m * 136 + j] = hb;
        }
    }
    __syncthreads();

    // ---- head: sHg from sHt (sH2 already holds lstm h) ----
    for (int i = tid; i < 2048; i += 512) {
        int k = i >> 4, r = i & 15;
        sHg[k * 16 + r] = bf2f(sHt[r * 136 + k]);
    }
    __syncthreads();

    {
        int ut = tid & 255, rg = tid >> 8;
        int u0 = ut * 2, rr0 = rg * 8;
        float acc[2][8] = {};
        for (int k = 0; k < 256; k++) {
            float2 w = *(const float2*)(WTf + k * 512 + u0);
            const float* ap = (k < 128) ? (sH2 + k * 20 + rr0)
                                        : (sHg + (k - 128) * 16 + rr0);
            float4 a0 = *(const float4*)(ap);
            float4 a1 = *(const float4*)(ap + 4);
            float av[8] = { a0.x, a0.y, a0.z, a0.w, a1.x, a1.y, a1.z, a1.w };
            #pragma unroll
            for (int rr = 0; rr < 8; rr++) {
                acc[0][rr] = fmaf(w.x, av[rr], acc[0][rr]);
                acc[1][rr] = fmaf(w.y, av[rr], acc[1][rr]);
            }
        }
        #pragma unroll
        for (int uu = 0; uu < 2; uu++) {
            int u = u0 + uu;
            float b = b1F[u];
            #pragma unroll
            for (int rr = 0; rr < 8; rr++) {
                int r = rr0 + rr;
                sHid[u * 16 + ((r + (u >> 1)) & 15)] = tanh_f(acc[uu][rr] + b);
            }
        }
    }
    __syncthreads();

    {
        int r = tid >> 3, i = tid & 7;
        float acc2 = 0.f;
        if (tid < 128) {
            acc2 = B2f[i];
            const float* wrp = W2f + i * 256;
            int ubase = (i < 7) ? 0 : 256;
            for (int k = 0; k < 256; k++) {
                int u = ubase + k;
                acc2 += wrp[k] * sHid[u * 16 + ((r + (u >> 1)) & 15)];
            }
            sScore[tid] = acc2;
        }
        __syncthreads();
        if (tid < 128) {
            const float* sr = sScore + r * 8;
            float m = sr[0];
            #pragma unroll
            for (int a = 1; a < 7; a++) m = fmaxf(m, sr[a]);
            float se = 0.f;
            #pragma unroll
            for (int a = 0; a < 7; a++) se += __expf(sr[a] - m);
            float lse = m + __logf(se);
            if (i < 7) out_lp[(rbase + r) * 7 + i] = acc2 - lse;
            else       out_val[rbase + r] = acc2;
        }
    }
}

// ======================================================================
extern "C" void kernel_launch(void* const* d_in, const int* in_sizes, int n_in,
                              void* d_out, int out_size, void* d_ws, size_t ws_size,
                              hipStream_t stream) {
    const int*  image  = (const int*)d_in[0];
    const void* memory = d_in[1];
    const int*  text   = (const int*)d_in[2];

    char* wsb = (char*)d_ws;
    float* ws0  = (float*)wsb;
    int*   flag = (int*)(wsb + WS_FLAG);

    float* out = (float*)d_out;
    float* out_lp  = out;
    float* out_val = out + OUT_VAL_OFF;
    float* mem_out = out + OUT_MEM_OFF;

    sniff_kernel<<<1, 256, 0, stream>>>((const unsigned short*)d_in[16], flag);

    const int PREP_GRID = (PREP_TASKS + 255) / 256;
    prep_kernel<true><<<PREP_GRID, 256, 0, stream>>>(flag,
        d_in[16], d_in[17], d_in[19], d_in[4], d_in[3], d_in[5],
        d_in[6], d_in[7], d_in[8], d_in[9], d_in[10], d_in[11],
        d_in[12], d_in[13], d_in[14], d_in[15],
        d_in[21], d_in[22], d_in[23], d_in[24],
        d_in[25], d_in[26], d_in[27], d_in[28],
        d_in[18], d_in[20], ws0);
    prep_kernel<false><<<PREP_GRID, 256, 0, stream>>>(flag,
        d_in[16], d_in[17], d_in[19], d_in[4], d_in[3], d_in[5],
        d_in[6], d_in[7], d_in[8], d_in[9], d_in[10], d_in[11],
        d_in[12], d_in[13], d_in[14], d_in[15],
        d_in[21], d_in[22], d_in[23], d_in[24],
        d_in[25], d_in[26], d_in[27], d_in[28],
        d_in[18], d_in[20], ws0);

    conv_kernel<<<Bsz / 8, 256, 0, stream>>>(image, ws0, mem_out);

    gru_head_kernel<<<GBLK, 512, 0, stream>>>(flag, text, memory, ws0,
                                              mem_out, out_lp, out_val);
}